// Round 4
// baseline (165.930 us; speedup 1.0000x reference)
//
#include <hip/hip_runtime.h>
#include <stdint.h>

// ---------- types ----------
typedef __bf16 bf16x8 __attribute__((ext_vector_type(8)));
typedef float f32x4 __attribute__((ext_vector_type(4)));
typedef float float4v __attribute__((ext_vector_type(4)));
typedef unsigned short u16x8 __attribute__((ext_vector_type(8)));

// round-to-nearest-even fp32 -> bf16
__device__ __forceinline__ unsigned short f2bf(float f) {
    unsigned u = __float_as_uint(f);
    u += 0x7fffu + ((u >> 16) & 1u);
    return (unsigned short)(u >> 16);
}

// fast stable softplus: max(x,0) + log(1+exp(-|x|))
__device__ __forceinline__ float softplus(float x) {
    return fmaxf(x, 0.0f) + __logf(1.0f + __expf(-fabsf(x)));
}

// async global->LDS, 16B per lane (gfx950). LDS dest must be wave-uniform
// base + lane*16 (lane-ordered, contiguous).
__device__ __forceinline__ void gl_lds16(const void* gptr, void* lptr) {
    auto g = reinterpret_cast<const __attribute__((address_space(1))) void*>(
        reinterpret_cast<uintptr_t>(gptr));
    auto l = reinterpret_cast<__attribute__((address_space(3))) void*>(
        reinterpret_cast<uintptr_t>(lptr));
    __builtin_amdgcn_global_load_lds(g, l, 16, 0, 0);
}

// ---------- fused prep: input f32->bf16  AND  w = mu + softplus(rho)*eps ----
__global__ void prep_kernel(const float* __restrict__ in,
                            const float* __restrict__ mu,
                            const float* __restrict__ rho,
                            const float* __restrict__ eps,
                            unsigned short* __restrict__ in_bf,
                            unsigned short* __restrict__ w_bf,
                            int nIn8, int nW8) {
    int i = blockIdx.x * blockDim.x + threadIdx.x;
    if (i < nIn8) {
        const float4v* p = (const float4v*)in + (size_t)i * 2;
        float4v a = p[0], b = p[1];
        u16x8 r;
        r[0] = f2bf(a[0]); r[1] = f2bf(a[1]); r[2] = f2bf(a[2]); r[3] = f2bf(a[3]);
        r[4] = f2bf(b[0]); r[5] = f2bf(b[1]); r[6] = f2bf(b[2]); r[7] = f2bf(b[3]);
        ((u16x8*)in_bf)[i] = r;
    } else {
        int j = i - nIn8;
        if (j >= nW8) return;
        const float4v* pm = (const float4v*)mu  + (size_t)j * 2;
        const float4v* pr = (const float4v*)rho + (size_t)j * 2;
        const float4v* pe = (const float4v*)eps + (size_t)j * 2;
        float4v m0 = pm[0], m1 = pm[1];
        float4v r0 = pr[0], r1 = pr[1];
        float4v e0 = pe[0], e1 = pe[1];
        u16x8 r;
        r[0] = f2bf(m0[0] + softplus(r0[0]) * e0[0]);
        r[1] = f2bf(m0[1] + softplus(r0[1]) * e0[1]);
        r[2] = f2bf(m0[2] + softplus(r0[2]) * e0[2]);
        r[3] = f2bf(m0[3] + softplus(r0[3]) * e0[3]);
        r[4] = f2bf(m1[0] + softplus(r1[0]) * e1[0]);
        r[5] = f2bf(m1[1] + softplus(r1[1]) * e1[1]);
        r[6] = f2bf(m1[2] + softplus(r1[2]) * e1[2]);
        r[7] = f2bf(m1[3] + softplus(r1[3]) * e1[3]);
        ((u16x8*)w_bf)[j] = r;
    }
}

// ---------- GEMM: C[M,N] = A[M,K] * B[N,K]^T + bias, bf16 in / f32 out -----
// DEEP-PIPELINED chunk ring (T3+T4+T5) + KC=32 XOR swizzle (this round):
//   - R3 counters: SQ_LDS_BANK_CONFLICT = 4.19M = 4 cyc per ds_read_b128.
//     Cause: 64 B row stride, no swizzle -> each quad's 16 lanes hit only
//     2 bank-quads (8 lanes/bank). Fix: XOR swizzle with key=(row>>1)&3,
//     phys_kg = kg ^ key. Read side: 16 lanes -> 8 distinct 16B slots,
//     2 lanes each = wave64 minimum (free). Write side: global_load_lds
//     dest stays LINEAR; the global SOURCE k-offset carries the inverse
//     permutation (same involution -- rule #21 both-sides-or-neither).
//     key invariant under row+64 and mi*16 -> one key per thread.
//   - 128x128 C-tile, 256 threads = 4 waves, wave tile 64x64 (8 ds_read_b128
//     per 16 MFMAs = 2.0 MFMA/read; conflict-free LDS 256 cy/blk-iter <
//     MFMA 310 cy -> MFMA-bound once conflicts are gone).
//   - K chunks of 32; 4-slot LDS ring (16 KB/slot, 64 KB, 2 blocks/CU).
//     3 chunks in flight; counted s_waitcnt vmcnt(12) -- never drained to 0
//     in the main loop, so ~900 cyc HBM latency spans 3 chunk windows.
//   - Raw s_barrier pairs: B_a after vmcnt (chunk readable), B_b after
//     lgkmcnt(0) (slot reusable). sched_barrier(0) pins inline-asm waits.
//   - s_setprio(1) around the MFMA cluster (T5).
//   - Tail: staged chunk index clamps to last chunk (uniform vmcnt count).
#define BM 128
#define BN 128
#define KC 32
#define SLOT_U 8192   // ushorts per ring slot: A 128*32 + B 128*32

__global__ __launch_bounds__(256, 2)
void gemm_bt_kernel(const unsigned short* __restrict__ A,   // [M,K] bf16
                    const unsigned short* __restrict__ B,   // [N,K] bf16
                    const float* __restrict__ bias,         // [N]
                    float* __restrict__ C,                  // [M,N] f32
                    int M, int N, int K) {
    __shared__ unsigned short lds[4][SLOT_U];   // 64 KB ring

    const int t      = threadIdx.x;
    const int lane   = t & 63;
    const int wave   = t >> 6;          // 0..3
    const int lane16 = lane & 15;
    const int quad   = lane >> 4;       // 0..3
    const int wm     = wave & 1;        // wave row: 0..1 (64 rows each)
    const int wn     = wave >> 1;       // wave col: 0..1 (64 cols each)

    const int m0 = blockIdx.y * BM;
    const int n0 = blockIdx.x * BN;

    // staging: chunk = A[128][32] + B[128][32] = 1024 x 16B, 256 thr -> 4 ea.
    // LDS dest linear (t*8); global source k-group carries the swizzle:
    // LDS slot (row, ps) holds logical k-group ps ^ ((row>>1)&3).
    const int r   = t >> 2;                       // 0..63
    const int key = (t >> 3) & 3;                 // (r>>1)&3, same for r+64
    const int kgs = ((t & 3) ^ key) * 8;          // swizzled k-elem offset

    const unsigned short* a0 = A + (size_t)(m0 + r)      * K + kgs;
    const unsigned short* a1 = A + (size_t)(m0 + 64 + r) * K + kgs;
    const unsigned short* b0 = B + (size_t)(n0 + r)      * K + kgs;
    const unsigned short* b1 = B + (size_t)(n0 + 64 + r) * K + kgs;

    f32x4 acc[4][4] = {};

    auto stage = [&](int slot, int kc) {
        const int k0 = kc * KC;
        gl_lds16(a0 + k0, &lds[slot][t * 8]);
        gl_lds16(a1 + k0, &lds[slot][2048 + t * 8]);
        gl_lds16(b0 + k0, &lds[slot][4096 + t * 8]);
        gl_lds16(b1 + k0, &lds[slot][6144 + t * 8]);
    };

    const int nchunk = K / KC;          // 64
    stage(0, 0);
    stage(1, 1);
    stage(2, 2);                        // 12 loads in flight

    // fragment read offsets (ushort idx), swizzled: phys_kg = quad ^ sw,
    // sw = (row>>1)&3 = (lane16>>1)&3 (invariant under wm*64 / mi*16).
    const int sw = (lane16 >> 1) & 3;
    const int ra = (wm * 64 + lane16) * KC + ((quad ^ sw) * 8);
    const int rb = 4096 + (wn * 64 + lane16) * KC + ((quad ^ sw) * 8);

#pragma unroll 4
    for (int i = 0; i < nchunk; ++i) {
        const int slot = i & 3;
        // issue stage for chunk i+3 into slot (i-1)&3 -- released by B_b(i-1)
        stage((i + 3) & 3, (i + 3 < nchunk) ? (i + 3) : (nchunk - 1));
        // chunk i landed for this wave (16 outstanding -> wait oldest 4)
        asm volatile("s_waitcnt vmcnt(12)" ::: "memory");
        __builtin_amdgcn_sched_barrier(0);
        __builtin_amdgcn_s_barrier();               // B_a: chunk i ready block-wide
        const unsigned short* ls = lds[slot];
        bf16x8 af[4], bf[4];
#pragma unroll
        for (int mi = 0; mi < 4; ++mi)
            af[mi] = *(const bf16x8*)(ls + ra + mi * 16 * KC);
#pragma unroll
        for (int ni = 0; ni < 4; ++ni)
            bf[ni] = *(const bf16x8*)(ls + rb + ni * 16 * KC);
        __builtin_amdgcn_s_setprio(1);
#pragma unroll
        for (int mi = 0; mi < 4; ++mi)
#pragma unroll
            for (int ni = 0; ni < 4; ++ni)
                acc[mi][ni] = __builtin_amdgcn_mfma_f32_16x16x32_bf16(
                    af[mi], bf[ni], acc[mi][ni], 0, 0, 0);
        __builtin_amdgcn_s_setprio(0);
        // ds_reads of chunk i fully complete before releasing the slot
        asm volatile("s_waitcnt lgkmcnt(0)" ::: "memory");
        __builtin_amdgcn_sched_barrier(0);
        __builtin_amdgcn_s_barrier();               // B_b: slot i&3 reusable
    }

    // epilogue: C/D layout col=lane&15, row=quad*4+reg (m89-verified)
    float bv[4];
#pragma unroll
    for (int ni = 0; ni < 4; ++ni)
        bv[ni] = bias[n0 + wn * 64 + ni * 16 + lane16];

#pragma unroll
    for (int mi = 0; mi < 4; ++mi) {
        const int rbase = m0 + wm * 64 + mi * 16 + quad * 4;
#pragma unroll
        for (int ni = 0; ni < 4; ++ni) {
            const int col = n0 + wn * 64 + ni * 16 + lane16;
#pragma unroll
            for (int rr = 0; rr < 4; ++rr)
                C[(size_t)(rbase + rr) * N + col] = acc[mi][ni][rr] + bv[ni];
        }
    }
}

extern "C" void kernel_launch(void* const* d_in, const int* in_sizes, int n_in,
                              void* d_out, int out_size, void* d_ws, size_t ws_size,
                              hipStream_t stream) {
    const float* input = (const float*)d_in[0];
    const float* mu    = (const float*)d_in[1];
    const float* rho   = (const float*)d_in[2];
    const float* eps   = (const float*)d_in[3];
    const float* bias  = (const float*)d_in[4];
    float* out = (float*)d_out;

    const int OUT = in_sizes[4];              // 2048
    const int IN  = in_sizes[1] / OUT;        // 2048
    const int M   = in_sizes[0] / IN;         // 4096

    unsigned short* in_bf = (unsigned short*)d_ws;                 // M*IN bf16
    unsigned short* w_bf  = in_bf + (size_t)M * IN;                // OUT*IN bf16

    const int nIn8 = (M * IN) / 8;
    const int nW8  = (OUT * IN) / 8;
    prep_kernel<<<dim3((nIn8 + nW8 + 255) / 256), 256, 0, stream>>>(
        input, mu, rho, eps, in_bf, w_bf, nIn8, nW8);

    gemm_bt_kernel<<<dim3(OUT / BN, M / BM), 256, 0, stream>>>(
        in_bf, w_bf, bias, out, M, OUT, IN);
}

// Round 5
// 165.765 us; speedup vs baseline: 1.0010x; 1.0010x over previous
//
#include <hip/hip_runtime.h>
#include <stdint.h>

// ---------- types ----------
typedef __bf16 bf16x8 __attribute__((ext_vector_type(8)));
typedef float f32x4 __attribute__((ext_vector_type(4)));
typedef float float4v __attribute__((ext_vector_type(4)));
typedef unsigned short u16x8 __attribute__((ext_vector_type(8)));

// round-to-nearest-even fp32 -> bf16
__device__ __forceinline__ unsigned short f2bf(float f) {
    unsigned u = __float_as_uint(f);
    u += 0x7fffu + ((u >> 16) & 1u);
    return (unsigned short)(u >> 16);
}

// fast stable softplus: max(x,0) + log(1+exp(-|x|))
__device__ __forceinline__ float softplus(float x) {
    return fmaxf(x, 0.0f) + __logf(1.0f + __expf(-fabsf(x)));
}

// async global->LDS, 16B per lane (gfx950). LDS dest must be wave-uniform
// base + lane*16 (lane-ordered, contiguous).
__device__ __forceinline__ void gl_lds16(const void* gptr, void* lptr) {
    auto g = reinterpret_cast<const __attribute__((address_space(1))) void*>(
        reinterpret_cast<uintptr_t>(gptr));
    auto l = reinterpret_cast<__attribute__((address_space(3))) void*>(
        reinterpret_cast<uintptr_t>(lptr));
    __builtin_amdgcn_global_load_lds(g, l, 16, 0, 0);
}

// ---------- fused prep: input f32->bf16  AND  w = mu + softplus(rho)*eps ----
__global__ void prep_kernel(const float* __restrict__ in,
                            const float* __restrict__ mu,
                            const float* __restrict__ rho,
                            const float* __restrict__ eps,
                            unsigned short* __restrict__ in_bf,
                            unsigned short* __restrict__ w_bf,
                            int nIn8, int nW8) {
    int i = blockIdx.x * blockDim.x + threadIdx.x;
    if (i < nIn8) {
        const float4v* p = (const float4v*)in + (size_t)i * 2;
        float4v a = p[0], b = p[1];
        u16x8 r;
        r[0] = f2bf(a[0]); r[1] = f2bf(a[1]); r[2] = f2bf(a[2]); r[3] = f2bf(a[3]);
        r[4] = f2bf(b[0]); r[5] = f2bf(b[1]); r[6] = f2bf(b[2]); r[7] = f2bf(b[3]);
        ((u16x8*)in_bf)[i] = r;
    } else {
        int j = i - nIn8;
        if (j >= nW8) return;
        const float4v* pm = (const float4v*)mu  + (size_t)j * 2;
        const float4v* pr = (const float4v*)rho + (size_t)j * 2;
        const float4v* pe = (const float4v*)eps + (size_t)j * 2;
        float4v m0 = pm[0], m1 = pm[1];
        float4v r0 = pr[0], r1 = pr[1];
        float4v e0 = pe[0], e1 = pe[1];
        u16x8 r;
        r[0] = f2bf(m0[0] + softplus(r0[0]) * e0[0]);
        r[1] = f2bf(m0[1] + softplus(r0[1]) * e0[1]);
        r[2] = f2bf(m0[2] + softplus(r0[2]) * e0[2]);
        r[3] = f2bf(m0[3] + softplus(r0[3]) * e0[3]);
        r[4] = f2bf(m1[0] + softplus(r1[0]) * e1[0]);
        r[5] = f2bf(m1[1] + softplus(r1[1]) * e1[1]);
        r[6] = f2bf(m1[2] + softplus(r1[2]) * e1[2]);
        r[7] = f2bf(m1[3] + softplus(r1[3]) * e1[3]);
        ((u16x8*)w_bf)[j] = r;
    }
}

// ---------- GEMM: C[M,N] = A[M,K] * B[N,K]^T + bias, bf16 in / f32 out -----
// REGISTER-DOUBLE-BUFFERED chunk ring (R5):
//   R4 counters: conflicts 0 but 1950 cy/chunk vs ~155 cy MFMA work -> the
//   per-iter serial chain {barrier, ds_read issue+latency, dependent MFMA,
//   barrier} was the cost, not LDS banks. Fix (m201 ordering): at half-iter
//   k issue ds_reads for chunk k+1 into the ALTERNATE fragment register set,
//   then run chunk k's 16 MFMAs from registers (reads & MFMAs interleave,
//   no dependency), then lgkmcnt(0). Read latency leaves the critical path.
//   Slot-lifetime proof: reads of slot s complete (lgkmcnt(0)) >= 2 barriers
//   before stage() rewrites s => ONE barrier per chunk suffices (was 2).
//   - vmcnt stays counted: stage -> vmcnt(8) waits only the oldest in-flight
//     chunk (3 chunks / 12 loads in flight; never drained to 0 in loop).
//   - KC=32 XOR swizzle kept (R4-verified: SQ_LDS_BANK_CONFLICT = 0):
//     key=(row>>1)&3, phys_kg = kg ^ key, applied to global SOURCE (write
//     side, LDS dest linear for global_load_lds) and to ds_read offsets.
//   - Fragment sets use LITERAL indices via macro (rule #20: runtime-indexed
//     ext_vector arrays go to scratch).
//   - sched_barrier(0) pins s_barrier/waitcnt ordering (rule #18).
//   - s_setprio(1) around the MFMA cluster (T5).
//   - Tail: read/stage chunk indices clamp to last chunk (uniform vmcnt
//     counts; redundant loads are L2-hits; dead reads go to the unused set).
#define BM 128
#define BN 128
#define KC 32
#define SLOT_U 8192   // ushorts per ring slot: A 128*32 + B 128*32

__global__ __launch_bounds__(256, 2)
void gemm_bt_kernel(const unsigned short* __restrict__ A,   // [M,K] bf16
                    const unsigned short* __restrict__ B,   // [N,K] bf16
                    const float* __restrict__ bias,         // [N]
                    float* __restrict__ C,                  // [M,N] f32
                    int M, int N, int K) {
    __shared__ unsigned short lds[4][SLOT_U];   // 64 KB ring

    const int t      = threadIdx.x;
    const int lane   = t & 63;
    const int wave   = t >> 6;          // 0..3
    const int lane16 = lane & 15;
    const int quad   = lane >> 4;       // 0..3
    const int wm     = wave & 1;        // wave row: 0..1 (64 rows each)
    const int wn     = wave >> 1;       // wave col: 0..1 (64 cols each)

    const int m0 = blockIdx.y * BM;
    const int n0 = blockIdx.x * BN;

    // staging: chunk = A[128][32] + B[128][32] = 1024 x 16B, 256 thr -> 4 ea.
    // LDS dest linear (t*8); global source k-group carries the swizzle:
    // LDS slot (row, ps) holds logical k-group ps ^ ((row>>1)&3).
    const int r   = t >> 2;                       // 0..63
    const int key = (t >> 3) & 3;                 // (r>>1)&3, same for r+64
    const int kgs = ((t & 3) ^ key) * 8;          // swizzled k-elem offset

    const unsigned short* a0 = A + (size_t)(m0 + r)      * K + kgs;
    const unsigned short* a1 = A + (size_t)(m0 + 64 + r) * K + kgs;
    const unsigned short* b0 = B + (size_t)(n0 + r)      * K + kgs;
    const unsigned short* b1 = B + (size_t)(n0 + 64 + r) * K + kgs;

    f32x4 acc[4][4] = {};

    auto stage = [&](int slot, int kc) {
        const int k0 = kc * KC;
        gl_lds16(a0 + k0, &lds[slot][t * 8]);
        gl_lds16(a1 + k0, &lds[slot][2048 + t * 8]);
        gl_lds16(b0 + k0, &lds[slot][4096 + t * 8]);
        gl_lds16(b1 + k0, &lds[slot][6144 + t * 8]);
    };

    const int nchunk = K / KC;          // 64 (even)

    // fragment read offsets (ushort idx), swizzled: phys_kg = quad ^ sw,
    // sw = (row>>1)&3 = (lane16>>1)&3 (invariant under wm*64 / mi*16).
    const int sw = (lane16 >> 1) & 3;
    const int ra = (wm * 64 + lane16) * KC + ((quad ^ sw) * 8);
    const int rb = 4096 + (wn * 64 + lane16) * KC + ((quad ^ sw) * 8);

    bf16x8 fA[2][4], fB[2][4];          // two fragment register sets

    // ---- prologue: 3 chunks in flight, read chunk 0 into set 0 ----
    stage(0, 0);
    stage(1, 1);
    stage(2, 2);                        // 12 loads outstanding
    asm volatile("s_waitcnt vmcnt(8)" ::: "memory");   // chunk 0 landed
    __builtin_amdgcn_sched_barrier(0);
    __builtin_amdgcn_s_barrier();
    __builtin_amdgcn_sched_barrier(0);
    {
        const unsigned short* ls0 = lds[0];
#pragma unroll
        for (int mi = 0; mi < 4; ++mi)
            fA[0][mi] = *(const bf16x8*)(ls0 + ra + mi * 16 * KC);
#pragma unroll
        for (int ni = 0; ni < 4; ++ni)
            fB[0][ni] = *(const bf16x8*)(ls0 + rb + ni * 16 * KC);
    }

// half-iter k: stage chunk k+3, read chunk k+1 -> set RD, MFMA chunk k set CP
#define HALF_ITER(RD, CP, kk)                                               \
    {                                                                       \
        const int k_ = (kk);                                                \
        stage((k_ + 3) & 3, (k_ + 3 < nchunk) ? (k_ + 3) : (nchunk - 1));   \
        asm volatile("s_waitcnt vmcnt(8)" ::: "memory");                    \
        __builtin_amdgcn_sched_barrier(0);                                  \
        __builtin_amdgcn_s_barrier();                                       \
        __builtin_amdgcn_sched_barrier(0);                                  \
        const int rc_ = (k_ + 1 < nchunk) ? (k_ + 1) : (nchunk - 1);        \
        const unsigned short* ls_ = lds[rc_ & 3];                           \
        _Pragma("unroll")                                                   \
        for (int mi = 0; mi < 4; ++mi)                                      \
            fA[RD][mi] = *(const bf16x8*)(ls_ + ra + mi * 16 * KC);         \
        _Pragma("unroll")                                                   \
        for (int ni = 0; ni < 4; ++ni)                                      \
            fB[RD][ni] = *(const bf16x8*)(ls_ + rb + ni * 16 * KC);         \
        __builtin_amdgcn_s_setprio(1);                                      \
        _Pragma("unroll")                                                   \
        for (int mi = 0; mi < 4; ++mi)                                      \
            _Pragma("unroll")                                               \
            for (int ni = 0; ni < 4; ++ni)                                  \
                acc[mi][ni] = __builtin_amdgcn_mfma_f32_16x16x32_bf16(      \
                    fA[CP][mi], fB[CP][ni], acc[mi][ni], 0, 0, 0);          \
        __builtin_amdgcn_s_setprio(0);                                      \
        asm volatile("s_waitcnt lgkmcnt(0)" ::: "memory");                  \
        __builtin_amdgcn_sched_barrier(0);                                  \
    }

    for (int k = 0; k < nchunk; k += 2) {
        HALF_ITER(1, 0, k);       // compute chunk k (set0), read k+1 -> set1
        HALF_ITER(0, 1, k + 1);   // compute chunk k+1 (set1), read k+2 -> set0
    }
#undef HALF_ITER

    // epilogue: C/D layout col=lane&15, row=quad*4+reg (m89-verified)
    float bv[4];
#pragma unroll
    for (int ni = 0; ni < 4; ++ni)
        bv[ni] = bias[n0 + wn * 64 + ni * 16 + lane16];

#pragma unroll
    for (int mi = 0; mi < 4; ++mi) {
        const int rbase = m0 + wm * 64 + mi * 16 + quad * 4;
#pragma unroll
        for (int ni = 0; ni < 4; ++ni) {
            const int col = n0 + wn * 64 + ni * 16 + lane16;
#pragma unroll
            for (int rr = 0; rr < 4; ++rr)
                C[(size_t)(rbase + rr) * N + col] = acc[mi][ni][rr] + bv[ni];
        }
    }
}

extern "C" void kernel_launch(void* const* d_in, const int* in_sizes, int n_in,
                              void* d_out, int out_size, void* d_ws, size_t ws_size,
                              hipStream_t stream) {
    const float* input = (const float*)d_in[0];
    const float* mu    = (const float*)d_in[1];
    const float* rho   = (const float*)d_in[2];
    const float* eps   = (const float*)d_in[3];
    const float* bias  = (const float*)d_in[4];
    float* out = (float*)d_out;

    const int OUT = in_sizes[4];              // 2048
    const int IN  = in_sizes[1] / OUT;        // 2048
    const int M   = in_sizes[0] / IN;         // 4096

    unsigned short* in_bf = (unsigned short*)d_ws;                 // M*IN bf16
    unsigned short* w_bf  = in_bf + (size_t)M * IN;                // OUT*IN bf16

    const int nIn8 = (M * IN) / 8;
    const int nW8  = (OUT * IN) / 8;
    prep_kernel<<<dim3((nIn8 + nW8 + 255) / 256), 256, 0, stream>>>(
        input, mu, rho, eps, in_bf, w_bf, nIn8, nW8);

    gemm_bt_kernel<<<dim3(OUT / BN, M / BM), 256, 0, stream>>>(
        in_bf, w_bf, bias, out, M, OUT, IN);
}

// Round 6
// 164.738 us; speedup vs baseline: 1.0072x; 1.0062x over previous
//
#include <hip/hip_runtime.h>
#include <stdint.h>

// ---------- types ----------
typedef __bf16 bf16x8 __attribute__((ext_vector_type(8)));
typedef float f32x4 __attribute__((ext_vector_type(4)));
typedef float float4v __attribute__((ext_vector_type(4)));
typedef unsigned short u16x8 __attribute__((ext_vector_type(8)));

// round-to-nearest-even fp32 -> bf16
__device__ __forceinline__ unsigned short f2bf(float f) {
    unsigned u = __float_as_uint(f);
    u += 0x7fffu + ((u >> 16) & 1u);
    return (unsigned short)(u >> 16);
}

// fast stable softplus: max(x,0) + log(1+exp(-|x|))
__device__ __forceinline__ float softplus(float x) {
    return fmaxf(x, 0.0f) + __logf(1.0f + __expf(-fabsf(x)));
}

// async global->LDS, 16B per lane (gfx950). LDS dest must be wave-uniform
// base + lane*16 (lane-ordered, contiguous).
__device__ __forceinline__ void gl_lds16(const void* gptr, void* lptr) {
    auto g = reinterpret_cast<const __attribute__((address_space(1))) void*>(
        reinterpret_cast<uintptr_t>(gptr));
    auto l = reinterpret_cast<__attribute__((address_space(3))) void*>(
        reinterpret_cast<uintptr_t>(lptr));
    __builtin_amdgcn_global_load_lds(g, l, 16, 0, 0);
}

// ---------- fused prep: input f32->bf16  AND  w = mu + softplus(rho)*eps ----
__global__ void prep_kernel(const float* __restrict__ in,
                            const float* __restrict__ mu,
                            const float* __restrict__ rho,
                            const float* __restrict__ eps,
                            unsigned short* __restrict__ in_bf,
                            unsigned short* __restrict__ w_bf,
                            int nIn8, int nW8) {
    int i = blockIdx.x * blockDim.x + threadIdx.x;
    if (i < nIn8) {
        const float4v* p = (const float4v*)in + (size_t)i * 2;
        float4v a = p[0], b = p[1];
        u16x8 r;
        r[0] = f2bf(a[0]); r[1] = f2bf(a[1]); r[2] = f2bf(a[2]); r[3] = f2bf(a[3]);
        r[4] = f2bf(b[0]); r[5] = f2bf(b[1]); r[6] = f2bf(b[2]); r[7] = f2bf(b[3]);
        ((u16x8*)in_bf)[i] = r;
    } else {
        int j = i - nIn8;
        if (j >= nW8) return;
        const float4v* pm = (const float4v*)mu  + (size_t)j * 2;
        const float4v* pr = (const float4v*)rho + (size_t)j * 2;
        const float4v* pe = (const float4v*)eps + (size_t)j * 2;
        float4v m0 = pm[0], m1 = pm[1];
        float4v r0 = pr[0], r1 = pr[1];
        float4v e0 = pe[0], e1 = pe[1];
        u16x8 r;
        r[0] = f2bf(m0[0] + softplus(r0[0]) * e0[0]);
        r[1] = f2bf(m0[1] + softplus(r0[1]) * e0[1]);
        r[2] = f2bf(m0[2] + softplus(r0[2]) * e0[2]);
        r[3] = f2bf(m0[3] + softplus(r0[3]) * e0[3]);
        r[4] = f2bf(m1[0] + softplus(r1[0]) * e1[0]);
        r[5] = f2bf(m1[1] + softplus(r1[1]) * e1[1]);
        r[6] = f2bf(m1[2] + softplus(r1[2]) * e1[2]);
        r[7] = f2bf(m1[3] + softplus(r1[3]) * e1[3]);
        ((u16x8*)w_bf)[j] = r;
    }
}

// ---------- GEMM: C[M,N] = A[M,K] * B[N,K]^T + bias, bf16 in / f32 out -----
// RING + FULL OCCUPANCY (R6):
//   R5 post-mortem: every ring refinement (swizzle, reg-dbuf, 1 barrier)
//   landed 48-52 us vs R0's 42 us; the one counter separating them is
//   OccupancyPercent 16.5 vs 33. Per SIMD per chunk-iter, MFMA work is
//   ~516 cy; measured iter ~1800 cy -- with 2 waves/SIMD nothing fills the
//   gap, with 4 waves/SIMD co-resident waves do. This round: SAME ring
//   schedule, 512 threads = 8 waves (wave tile 64x32 = R0's verified
//   geometry), launch_bounds(512,4) -> 2 blocks/CU -> 16 waves/CU.
//   - K chunks of 32; 4-slot LDS ring (16 KB/slot, 64 KB, 2 blocks/CU).
//     3 chunks in flight; counted s_waitcnt vmcnt(4) (2 loads/stage now) --
//     never drained to 0 in the main loop.
//   - Reg-double-buffered fragments: read chunk k+1 while MFMAing chunk k;
//     ONE raw s_barrier per chunk (slot-lifetime proof in R5, unchanged).
//   - KC=32 XOR swizzle kept (R4-verified: 0 conflicts): key=(row>>1)&3,
//     applied to global SOURCE k-group (LDS dest linear) and ds_read offs.
//     Invariance: row shifts of 16/32/64 leave (row>>1)&3 unchanged.
//   - LITERAL fragment-set indices via macro (rule #20); sched_barrier(0)
//     pins inline-asm waits (rule #18); s_setprio around MFMAs (T5).
//   - Tail: stage/read chunk indices clamp to last chunk (uniform vmcnt).
#define BM 128
#define BN 128
#define KC 32
#define SLOT_U 8192   // ushorts per ring slot: A 128*32 + B 128*32

__global__ __launch_bounds__(512, 4)
void gemm_bt_kernel(const unsigned short* __restrict__ A,   // [M,K] bf16
                    const unsigned short* __restrict__ B,   // [N,K] bf16
                    const float* __restrict__ bias,         // [N]
                    float* __restrict__ C,                  // [M,N] f32
                    int M, int N, int K) {
    __shared__ unsigned short lds[4][SLOT_U];   // 64 KB ring

    const int t      = threadIdx.x;
    const int lane   = t & 63;
    const int wave   = t >> 6;          // 0..7
    const int lane16 = lane & 15;
    const int quad   = lane >> 4;       // 0..3
    const int wm     = wave & 1;        // wave row: 0..1 (64 rows each)
    const int wn     = wave >> 1;       // wave col: 0..3 (32 cols each)

    const int m0 = blockIdx.y * BM;
    const int n0 = blockIdx.x * BN;

    // staging: chunk = A[128][32] + B[128][32] = 2 x 512 x 16B, 512 thr ->
    // 1 A-piece + 1 B-piece each. LDS dest linear (t*8); global source
    // k-group carries the swizzle: slot (row, ps) holds kg ps ^ ((row>>1)&3).
    const int r   = t >> 2;                       // 0..127
    const int key = (t >> 3) & 3;                 // (r>>1)&3
    const int kgs = ((t & 3) ^ key) * 8;          // swizzled k-elem offset

    const unsigned short* a0 = A + (size_t)(m0 + r) * K + kgs;
    const unsigned short* b0 = B + (size_t)(n0 + r) * K + kgs;

    f32x4 acc[4][2] = {};

    auto stage = [&](int slot, int kc) {
        const int k0 = kc * KC;
        gl_lds16(a0 + k0, &lds[slot][t * 8]);
        gl_lds16(b0 + k0, &lds[slot][4096 + t * 8]);
    };

    const int nchunk = K / KC;          // 64 (even)

    // fragment read offsets (ushort idx), swizzled: phys_kg = quad ^ sw,
    // sw = (row>>1)&3 = (lane16>>1)&3 (invariant under wm*64/wn*32/mi*16).
    const int sw = (lane16 >> 1) & 3;
    const int ra = (wm * 64 + lane16) * KC + ((quad ^ sw) * 8);
    const int rb = 4096 + (wn * 32 + lane16) * KC + ((quad ^ sw) * 8);

    bf16x8 fA[2][4], fB[2][2];          // two fragment register sets

    // ---- prologue: 3 chunks in flight, read chunk 0 into set 0 ----
    stage(0, 0);
    stage(1, 1);
    stage(2, 2);                        // 6 loads outstanding
    asm volatile("s_waitcnt vmcnt(4)" ::: "memory");   // chunk 0 landed
    __builtin_amdgcn_sched_barrier(0);
    __builtin_amdgcn_s_barrier();
    __builtin_amdgcn_sched_barrier(0);
    {
        const unsigned short* ls0 = lds[0];
#pragma unroll
        for (int mi = 0; mi < 4; ++mi)
            fA[0][mi] = *(const bf16x8*)(ls0 + ra + mi * 16 * KC);
#pragma unroll
        for (int ni = 0; ni < 2; ++ni)
            fB[0][ni] = *(const bf16x8*)(ls0 + rb + ni * 16 * KC);
    }

// half-iter k: stage chunk k+3, read chunk k+1 -> set RD, MFMA chunk k set CP
#define HALF_ITER(RD, CP, kk)                                               \
    {                                                                       \
        const int k_ = (kk);                                                \
        stage((k_ + 3) & 3, (k_ + 3 < nchunk) ? (k_ + 3) : (nchunk - 1));   \
        asm volatile("s_waitcnt vmcnt(4)" ::: "memory");                    \
        __builtin_amdgcn_sched_barrier(0);                                  \
        __builtin_amdgcn_s_barrier();                                       \
        __builtin_amdgcn_sched_barrier(0);                                  \
        const int rc_ = (k_ + 1 < nchunk) ? (k_ + 1) : (nchunk - 1);        \
        const unsigned short* ls_ = lds[rc_ & 3];                           \
        _Pragma("unroll")                                                   \
        for (int mi = 0; mi < 4; ++mi)                                      \
            fA[RD][mi] = *(const bf16x8*)(ls_ + ra + mi * 16 * KC);         \
        _Pragma("unroll")                                                   \
        for (int ni = 0; ni < 2; ++ni)                                      \
            fB[RD][ni] = *(const bf16x8*)(ls_ + rb + ni * 16 * KC);         \
        __builtin_amdgcn_s_setprio(1);                                      \
        _Pragma("unroll")                                                   \
        for (int mi = 0; mi < 4; ++mi)                                      \
            _Pragma("unroll")                                               \
            for (int ni = 0; ni < 2; ++ni)                                  \
                acc[mi][ni] = __builtin_amdgcn_mfma_f32_16x16x32_bf16(      \
                    fA[CP][mi], fB[CP][ni], acc[mi][ni], 0, 0, 0);          \
        __builtin_amdgcn_s_setprio(0);                                      \
        asm volatile("s_waitcnt lgkmcnt(0)" ::: "memory");                  \
        __builtin_amdgcn_sched_barrier(0);                                  \
    }

    for (int k = 0; k < nchunk; k += 2) {
        HALF_ITER(1, 0, k);       // compute chunk k (set0), read k+1 -> set1
        HALF_ITER(0, 1, k + 1);   // compute chunk k+1 (set1), read k+2 -> set0
    }
#undef HALF_ITER

    // epilogue: C/D layout col=lane&15, row=quad*4+reg (m89-verified)
    float bv[2];
#pragma unroll
    for (int ni = 0; ni < 2; ++ni)
        bv[ni] = bias[n0 + wn * 32 + ni * 16 + lane16];

#pragma unroll
    for (int mi = 0; mi < 4; ++mi) {
        const int rbase = m0 + wm * 64 + mi * 16 + quad * 4;
#pragma unroll
        for (int ni = 0; ni < 2; ++ni) {
            const int col = n0 + wn * 32 + ni * 16 + lane16;
#pragma unroll
            for (int rr = 0; rr < 4; ++rr)
                C[(size_t)(rbase + rr) * N + col] = acc[mi][ni][rr] + bv[ni];
        }
    }
}

extern "C" void kernel_launch(void* const* d_in, const int* in_sizes, int n_in,
                              void* d_out, int out_size, void* d_ws, size_t ws_size,
                              hipStream_t stream) {
    const float* input = (const float*)d_in[0];
    const float* mu    = (const float*)d_in[1];
    const float* rho   = (const float*)d_in[2];
    const float* eps   = (const float*)d_in[3];
    const float* bias  = (const float*)d_in[4];
    float* out = (float*)d_out;

    const int OUT = in_sizes[4];              // 2048
    const int IN  = in_sizes[1] / OUT;        // 2048
    const int M   = in_sizes[0] / IN;         // 4096

    unsigned short* in_bf = (unsigned short*)d_ws;                 // M*IN bf16
    unsigned short* w_bf  = in_bf + (size_t)M * IN;                // OUT*IN bf16

    const int nIn8 = (M * IN) / 8;
    const int nW8  = (OUT * IN) / 8;
    prep_kernel<<<dim3((nIn8 + nW8 + 255) / 256), 256, 0, stream>>>(
        input, mu, rho, eps, in_bf, w_bf, nIn8, nW8);

    gemm_bt_kernel<<<dim3(OUT / BN, M / BM), 512, 0, stream>>>(
        in_bf, w_bf, bias, out, M, OUT, IN);
}